// Round 7
// baseline (1068.502 us; speedup 1.0000x reference)
//
#include <hip/hip_runtime.h>
#include <float.h>
#include <stdint.h>

// Problem constants
constexpr int D      = 256;
constexpr int K      = 8192;
constexpr int NROWS  = 16384;   // 16 * 32 * 32
constexpr int BHW    = 1024;
constexpr int CAP    = 128;     // max candidates per row (64 blocks * 2)
constexpr float MARGIN = 8e-4f; // >= 2E = 5.8e-4 rigorous bound (see notes)

typedef __bf16 bf16x8 __attribute__((ext_vector_type(8)));
typedef float  f32x4  __attribute__((ext_vector_type(4)));
typedef unsigned short ushort4v __attribute__((ext_vector_type(4)));

// ---- contraction-proof f32 ops (round exactly like numpy's elementwise)
__device__ __forceinline__ float mul_rn(float a, float b) {
#pragma clang fp contract(off)
    return a * b;
}
__device__ __forceinline__ float add_rn(float a, float b) {
#pragma clang fp contract(off)
    return a + b;
}
__device__ __forceinline__ float sub_rn(float a, float b) {
#pragma clang fp contract(off)
    return a - b;
}

__device__ __forceinline__ unsigned short f32_bf16_rn(float f) {
    unsigned u = __float_as_uint(f);
    return (unsigned short)((u + 0x7FFFu + ((u >> 16) & 1u)) >> 16);
}

// sorted-3 insert: keep 3 smallest, indices for slots 0,1 only
__device__ __forceinline__ void ins3(float s, int kg, float& v0, int& i0,
                                     float& v1, int& i1, float& v2) {
    if (s < v0)      { v2 = v1; v1 = v0; i1 = i0; v0 = s; i0 = kg; }
    else if (s < v1) { v2 = v1; v1 = s; i1 = kg; }
    else if (s < v2) { v2 = s; }
}

// numpy pairwise_sum replica for 256 f32 squares (8 chains stride 8, tree merge)
template <typename LOAD>
__device__ __forceinline__ float np_sumsq_256(LOAD ld) {
    float blk[2];
    #pragma unroll
    for (int h = 0; h < 2; ++h) {
        const int base = h * 128;
        float r[8];
        #pragma unroll
        for (int j = 0; j < 8; ++j) {
            float v = ld(base + j);
            r[j] = mul_rn(v, v);
        }
        for (int i = 8; i < 128; i += 8) {
            #pragma unroll
            for (int j = 0; j < 8; ++j) {
                float v = ld(base + i + j);
                r[j] = add_rn(r[j], mul_rn(v, v));
            }
        }
        blk[h] = add_rn(add_rn(add_rn(r[0], r[1]), add_rn(r[2], r[3])),
                        add_rn(add_rn(r[4], r[5]), add_rn(r[6], r[7])));
    }
    return add_rn(blk[0], blk[1]);
}

// ---------------- K1: x (B,C,H,W) -> xT[n][256] f32 + Xbf[n][256] bf16
__global__ __launch_bounds__(256)
void prep_x_kernel(const float* __restrict__ x, float* __restrict__ xT,
                   unsigned short* __restrict__ Xbf) {
    __shared__ float t[32][33];
    const int tid = threadIdx.x;
    const int tx = tid & 31, ty = tid >> 5;
    const int ht = blockIdx.x & 31;
    const int dt = (blockIdx.x >> 5) & 7;
    const int b  = blockIdx.x >> 8;
    #pragma unroll
    for (int r = 0; r < 4; ++r) {
        int dl = ty + 8 * r;
        t[dl][tx] = x[(size_t)(b * 256 + dt * 32 + dl) * BHW + ht * 32 + tx];
    }
    __syncthreads();
    #pragma unroll
    for (int r = 0; r < 4; ++r) {
        int hwl = ty + 8 * r;
        int n = b * BHW + ht * 32 + hwl;
        float f = t[tx][hwl];
        xT[(size_t)n * 256 + dt * 32 + tx] = f;
        Xbf[(size_t)n * 256 + dt * 32 + tx] = f32_bf16_rn(f);
    }
}

// ---------------- K2: cb -> Cbf bf16
__global__ __launch_bounds__(256)
void prep_c_kernel(const float* __restrict__ cb, unsigned short* __restrict__ Cbf) {
    int t = blockIdx.x * 256 + threadIdx.x;   // one float4 (524288 total)
    float4 v = ((const float4*)cb)[t];
    ushort4v h;
    h.x = f32_bf16_rn(v.x); h.y = f32_bf16_rn(v.y);
    h.z = f32_bf16_rn(v.z); h.w = f32_bf16_rn(v.w);
    *(ushort4v*)(Cbf + (size_t)t * 4) = h;
}

// ---------------- K3: c_sq (np-exact)
__global__ __launch_bounds__(256)
void csq_kernel(const float* __restrict__ cb, float* __restrict__ csq) {
    int k = blockIdx.x * 256 + threadIdx.x;
    if (k >= K) return;
    const float* row = cb + (size_t)k * D;
    csq[k] = np_sumsq_256([&](int d) { return row[d]; });
}

// ---------------- K4: x_sq (np-exact, from xT)
__global__ __launch_bounds__(256)
void xsq_kernel(const float* __restrict__ xT, float* __restrict__ xsq) {
    int n = blockIdx.x * 256 + threadIdx.x;
    if (n >= NROWS) return;
    const float* row = xT + (size_t)n * 256;
    xsq[n] = np_sumsq_256([&](int d) { return row[d]; });
}

// ---------------- K5: bf16 MFMA screen, top-3 per (row, 128-code block)
// s~[n][k] = csq[k] - 2*dot_bf16(x[n],c[k]);  outputs laid out [block][n]
// NO LDS in the K-loop: A/B fragments are 16B-contiguous in Xbf/Cbf and are
// loaded straight from global (coalesced 16 B/lane) -> zero barriers.
__global__ __launch_bounds__(256)
void screen_kernel(const unsigned short* __restrict__ Xbf,  // [16384][256]
                   const unsigned short* __restrict__ Cbf,  // [8192][256]
                   const float* __restrict__ csq,
                   float* __restrict__ sv0, float* __restrict__ sv1,
                   float* __restrict__ sv2,
                   int* __restrict__ si0, int* __restrict__ si1) {
    __shared__ float lmv0[256], lmv1[256], lmv2[256];
    __shared__ int   lmi0[256], lmi1[256];

    const int tid = threadIdx.x;
    const int w   = tid >> 6;
    const int ln  = tid & 63;
    const int bx = blockIdx.x, by = blockIdx.y;

    const int rh = (w & 1) * 64;    // wave's row half
    const int ch = (w >> 1) * 64;   // wave's col half

    // fragment base rows (16x16x32 A/B layout: 16 B contiguous per lane)
    const int row0 = bx * 128 + rh + (ln & 15);
    const int col0 = by * 128 + ch + (ln & 15);
    const int kq   = (ln >> 4) * 8;             // k-offset within 32-step
    const unsigned short* pa = Xbf + (size_t)row0 * 256 + kq;
    const unsigned short* pb = Cbf + (size_t)col0 * 256 + kq;

    f32x4 acc[4][4] = {};

    #pragma unroll 4
    for (int ks = 0; ks < 8; ++ks) {            // K = 256, 32 per step
        const int kb = ks * 32;
        bf16x8 af[4], bfr[4];
        #pragma unroll
        for (int t = 0; t < 4; ++t) {
            af[t]  = *(const bf16x8*)(pa + (size_t)(t * 16) * 256 + kb);
            bfr[t] = *(const bf16x8*)(pb + (size_t)(t * 16) * 256 + kb);
        }
        #pragma unroll
        for (int i = 0; i < 4; ++i)
            #pragma unroll
            for (int j = 0; j < 4; ++j)
                acc[i][j] = __builtin_amdgcn_mfma_f32_16x16x32_bf16(af[i], bfr[j], acc[i][j], 0, 0, 0);
    }

    // epilogue: per (row, this wave's 64 cols) top-3 with indices for top-2
    float cq[4];
    #pragma unroll
    for (int j = 0; j < 4; ++j)
        cq[j] = csq[by * 128 + ch + j * 16 + (ln & 15)];

    #pragma unroll
    for (int i = 0; i < 4; ++i)
        #pragma unroll
        for (int r = 0; r < 4; ++r) {
            float v0 = FLT_MAX, v1 = FLT_MAX, v2 = FLT_MAX;
            int i0 = 0, i1 = 0;
            #pragma unroll
            for (int j = 0; j < 4; ++j) {
                float s = cq[j] - 2.0f * acc[i][j][r];
                int kg = by * 128 + ch + j * 16 + (ln & 15);
                ins3(s, kg, v0, i0, v1, i1, v2);
            }
            #pragma unroll
            for (int m = 1; m < 16; m <<= 1) {
                float w0 = __shfl_xor(v0, m, 64); int u0 = __shfl_xor(i0, m, 64);
                float w1 = __shfl_xor(v1, m, 64); int u1 = __shfl_xor(i1, m, 64);
                float w2 = __shfl_xor(v2, m, 64);
                ins3(w0, u0, v0, i0, v1, i1, v2);
                ins3(w1, u1, v0, i0, v1, i1, v2);
                v2 = fminf(v2, w2);
            }
            if ((ln & 15) == 0) {
                int lrow = rh + i * 16 + (ln >> 4) * 4 + r;
                int half = w >> 1;
                lmv0[lrow * 2 + half] = v0;
                lmv1[lrow * 2 + half] = v1;
                lmv2[lrow * 2 + half] = v2;
                lmi0[lrow * 2 + half] = i0;
                lmi1[lrow * 2 + half] = i1;
            }
        }
    __syncthreads();
    if (tid < 128) {
        float v0 = lmv0[tid * 2], v1 = lmv1[tid * 2], v2 = lmv2[tid * 2];
        int i0 = lmi0[tid * 2], i1 = lmi1[tid * 2];
        ins3(lmv0[tid * 2 + 1], lmi0[tid * 2 + 1], v0, i0, v1, i1, v2);
        ins3(lmv1[tid * 2 + 1], lmi1[tid * 2 + 1], v0, i0, v1, i1, v2);
        v2 = fminf(v2, lmv2[tid * 2 + 1]);
        size_t o = (size_t)by * NROWS + bx * 128 + tid;
        sv0[o] = v0; sv1[o] = v1; sv2[o] = v2; si0[o] = i0; si1[o] = i1;
    }
}

// ---------------- K6: per-row thresh + candidate list (+ rare full-scan mask)
__global__ __launch_bounds__(256)
void flag_kernel(const float* __restrict__ sv0, const float* __restrict__ sv1,
                 const float* __restrict__ sv2,
                 const int* __restrict__ si0, const int* __restrict__ si1,
                 int* __restrict__ cand, int* __restrict__ count,
                 unsigned long long* __restrict__ fsmask) {
    __shared__ float tile[64][65];
    __shared__ float thrS[64];
    __shared__ unsigned long long m1s[64], m2s[64], m3s[64];
    const int tid = threadIdx.x;
    const int ln = tid & 63, w = tid >> 6;
    const int n0 = blockIdx.x * 64;

    for (int b = w; b < 64; b += 4) tile[ln][b] = sv0[(size_t)b * NROWS + n0 + ln];
    __syncthreads();
    for (int rr = 0; rr < 16; ++rr) {
        int row = w * 16 + rr;
        float v = tile[row][ln];
        float g = v;
        #pragma unroll
        for (int m = 1; m < 64; m <<= 1) g = fminf(g, __shfl_xor(g, m, 64));
        float th = g + MARGIN;
        unsigned long long m1 = __ballot(v <= th);
        if (ln == 0) { thrS[row] = th; m1s[row] = m1; }
    }
    __syncthreads();
    for (int b = w; b < 64; b += 4) tile[ln][b] = sv1[(size_t)b * NROWS + n0 + ln];
    __syncthreads();
    for (int rr = 0; rr < 16; ++rr) {
        int row = w * 16 + rr;
        unsigned long long m2 = __ballot(tile[row][ln] <= thrS[row]);
        if (ln == 0) m2s[row] = m2;
    }
    __syncthreads();
    for (int b = w; b < 64; b += 4) tile[ln][b] = sv2[(size_t)b * NROWS + n0 + ln];
    __syncthreads();
    for (int rr = 0; rr < 16; ++rr) {
        int row = w * 16 + rr;
        unsigned long long m3 = __ballot(tile[row][ln] <= thrS[row]);
        if (ln == 0) m3s[row] = m3;
    }
    __syncthreads();
    for (int rr = 0; rr < 16; ++rr) {
        int row = w * 16 + rr;
        int n = n0 + row;
        unsigned long long m1 = m1s[row], m2 = m2s[row];
        int c1 = __popcll(m1);
        if ((m1 >> ln) & 1) {
            int pos = __popcll(m1 & ((1ull << ln) - 1ull));
            cand[(size_t)n * CAP + pos] = si0[(size_t)ln * NROWS + n];
        }
        if ((m2 >> ln) & 1) {
            int pos = c1 + __popcll(m2 & ((1ull << ln) - 1ull));
            cand[(size_t)n * CAP + pos] = si1[(size_t)ln * NROWS + n];
        }
        if (ln == 0) {
            count[n] = c1 + __popcll(m2);
            fsmask[n] = m3s[row];
        }
    }
}

// ---------------- K7: exact rescore of candidate codes -> idx[n]
__global__ __launch_bounds__(256)
void rescore_kernel(const float* __restrict__ xT, const float* __restrict__ cb,
                    const float* __restrict__ csq, const float* __restrict__ xsq,
                    const int* __restrict__ cand, const int* __restrict__ count,
                    const unsigned long long* __restrict__ fsmask,
                    int* __restrict__ idx) {
    const int tid = threadIdx.x;
    const int w = tid >> 6, ln = tid & 63;
    const int n = blockIdx.x * 4 + w;
    float4 xv = ((const float4*)xT)[(size_t)n * 64 + ln];
    const float xs = xsq[n];
    const int cnt = count[n];
    unsigned long long fs = fsmask[n];
    float bs = FLT_MAX;
    int   bk = 0x7fffffff;
    auto eval = [&](int k) {
        float4 cv = ((const float4*)cb)[(size_t)k * 64 + ln];
        double d = (double)cv.x * xv.x + (double)cv.y * xv.y
                 + (double)cv.z * xv.z + (double)cv.w * xv.w;
        #pragma unroll
        for (int m = 1; m < 64; m <<= 1) d += __shfl_xor(d, m, 64);
        float s = sub_rn(add_rn(xs, csq[k]), mul_rn(2.0f, (float)d));
        if (s < bs || (s == bs && k < bk)) { bs = s; bk = k; }
    };
    for (int c = 0; c < cnt; ++c) eval(cand[(size_t)n * CAP + c]);
    while (fs) {           // rare rigorous fallback: >2 near-ties in one block
        int b = (int)__builtin_ctzll(fs);
        fs &= fs - 1;
        for (int kk = 0; kk < 128; ++kk) eval(b * 128 + kk);
    }
    if (ln == 0) idx[n] = bk;
}

// ---------------- K8: quantized gather back to (B,C,H,W)
__global__ __launch_bounds__(256)
void gather_quant_kernel(const float* __restrict__ cb, const int* __restrict__ idx,
                         float* __restrict__ out0) {
    int t = blockIdx.x * 256 + threadIdx.x;
    int hw4 = t & 255;
    int d   = (t >> 8) & 255;
    int b   = t >> 16;
    int n0  = b * BHW + hw4 * 4;
    float4 o;
    o.x = cb[(size_t)idx[n0 + 0] * D + d];
    o.y = cb[(size_t)idx[n0 + 1] * D + d];
    o.z = cb[(size_t)idx[n0 + 2] * D + d];
    o.w = cb[(size_t)idx[n0 + 3] * D + d];
    ((float4*)out0)[t] = o;
}

// ---------------- K9: one-hot fill
__global__ __launch_bounds__(256)
void onehot_kernel(const int* __restrict__ idx, float* __restrict__ out1) {
    int t = blockIdx.x * 256 + threadIdx.x;
    int n  = t >> 11;
    int k0 = (t & 2047) * 4;
    int target = idx[n];
    float4 v = {0.f, 0.f, 0.f, 0.f};
    int r = target - k0;
    if (r >= 0 && r < 4) ((float*)&v)[r] = 1.0f;
    ((float4*)out1)[t] = v;
}

// ------------------------------------------------------------------ launch
extern "C" void kernel_launch(void* const* d_in, const int* in_sizes, int n_in,
                              void* d_out, int out_size, void* d_ws, size_t ws_size,
                              hipStream_t stream) {
    const float* x  = (const float*)d_in[0];   // [16][256][32][32]
    const float* cb = (const float*)d_in[1];   // [8192][256]
    float* out0 = (float*)d_out;                       // quantized
    float* out1 = (float*)d_out + 4194304;             // one_hot (537 MB)

    // small scratch in ws
    char* ws = (char*)d_ws;
    float* csq  = (float*)(ws + 0);            //  32 KB
    float* xsq  = (float*)(ws + 32768);        //  64 KB
    int*   idx  = (int*)  (ws + 98304);        //  64 KB
    int*   cnt  = (int*)  (ws + 163840);       //  64 KB
    unsigned long long* fsm = (unsigned long long*)(ws + 229376);  // 128 KB

    // big scratch in the one_hot region (fully overwritten last by onehot)
    char* sc = (char*)out1;
    unsigned short* Xbf = (unsigned short*)sc;                   //  8 MB
    unsigned short* Cbf = (unsigned short*)(sc + 8388608);       //  4 MB
    float* xT  = (float*)(sc + 12582912);                        // 16 MB
    float* sv0 = (float*)(sc + 29360128);                        //  4 MB
    float* sv1 = (float*)(sc + 33554432);
    float* sv2 = (float*)(sc + 37748736);
    int*   si0 = (int*)  (sc + 41943040);
    int*   si1 = (int*)  (sc + 46137344);
    int*   cand = (int*) (sc + 50331648);                        //  8 MB

    prep_x_kernel<<<4096, 256, 0, stream>>>(x, xT, Xbf);
    prep_c_kernel<<<2048, 256, 0, stream>>>(cb, Cbf);
    csq_kernel<<<K / 256, 256, 0, stream>>>(cb, csq);
    xsq_kernel<<<NROWS / 256, 256, 0, stream>>>(xT, xsq);

    dim3 sgrid(NROWS / 128, K / 128);   // 128 x 64
    screen_kernel<<<sgrid, 256, 0, stream>>>(Xbf, Cbf, csq, sv0, sv1, sv2, si0, si1);

    flag_kernel<<<NROWS / 64, 256, 0, stream>>>(sv0, sv1, sv2, si0, si1, cand, cnt, fsm);
    rescore_kernel<<<NROWS / 4, 256, 0, stream>>>(xT, cb, csq, xsq, cand, cnt, fsm, idx);

    gather_quant_kernel<<<(4194304 / 4) / 256, 256, 0, stream>>>(cb, idx, out0);
    onehot_kernel<<<(134217728 / 4) / 256, 256, 0, stream>>>(idx, out1);
}

// Round 8
// 957.134 us; speedup vs baseline: 1.1164x; 1.1164x over previous
//
#include <hip/hip_runtime.h>
#include <float.h>
#include <stdint.h>

// Problem constants
constexpr int D      = 256;
constexpr int K      = 8192;
constexpr int NROWS  = 16384;   // 16 * 32 * 32
constexpr int BHW    = 1024;
constexpr float MARGIN = 8e-4f; // rigorous need: 5.8e-4 (2*bf16 err + 2 buckets) + pack slop

typedef __bf16 bf16x8 __attribute__((ext_vector_type(8)));
typedef float  f32x4  __attribute__((ext_vector_type(4)));
typedef unsigned short ushort4v __attribute__((ext_vector_type(4)));

// ---- contraction-proof f32 ops (round exactly like numpy's elementwise)
__device__ __forceinline__ float mul_rn(float a, float b) {
#pragma clang fp contract(off)
    return a * b;
}
__device__ __forceinline__ float add_rn(float a, float b) {
#pragma clang fp contract(off)
    return a + b;
}
__device__ __forceinline__ float sub_rn(float a, float b) {
#pragma clang fp contract(off)
    return a - b;
}

__device__ __forceinline__ unsigned short f32_bf16_rn(float f) {
    unsigned u = __float_as_uint(f);
    return (unsigned short)((u + 0x7FFFu + ((u >> 16) & 1u)) >> 16);
}

__device__ __forceinline__ unsigned umin_(unsigned a, unsigned b) { return a < b ? a : b; }
__device__ __forceinline__ unsigned umax_(unsigned a, unsigned b) { return a > b ? a : b; }

// monotone float->u32 key: order(key) == order(float)
__device__ __forceinline__ unsigned mono_key(float s) {
    unsigned b = __float_as_uint(s);
    return b ^ ((unsigned)((int)b >> 31) | 0x80000000u);
}
__device__ __forceinline__ float inv_mono(unsigned k) {
    unsigned m = (k & 0x80000000u) ? 0x80000000u : 0xFFFFFFFFu;
    return __uint_as_float(k ^ m);
}

// ---------------- K1: x (B,C,H,W) -> xT[n][256] f32 + Xbf[n][256] bf16
__global__ __launch_bounds__(256)
void prep_x_kernel(const float* __restrict__ x, float* __restrict__ xT,
                   unsigned short* __restrict__ Xbf) {
    __shared__ float t[32][33];
    const int tid = threadIdx.x;
    const int tx = tid & 31, ty = tid >> 5;
    const int ht = blockIdx.x & 31;
    const int dt = (blockIdx.x >> 5) & 7;
    const int b  = blockIdx.x >> 8;
    #pragma unroll
    for (int r = 0; r < 4; ++r) {
        int dl = ty + 8 * r;
        t[dl][tx] = x[(size_t)(b * 256 + dt * 32 + dl) * BHW + ht * 32 + tx];
    }
    __syncthreads();
    #pragma unroll
    for (int r = 0; r < 4; ++r) {
        int hwl = ty + 8 * r;
        int n = b * BHW + ht * 32 + hwl;
        float f = t[tx][hwl];
        xT[(size_t)n * 256 + dt * 32 + tx] = f;
        Xbf[(size_t)n * 256 + dt * 32 + tx] = f32_bf16_rn(f);
    }
}

// ---------------- K2: cb -> Cbf bf16
__global__ __launch_bounds__(256)
void prep_c_kernel(const float* __restrict__ cb, unsigned short* __restrict__ Cbf) {
    int t = blockIdx.x * 256 + threadIdx.x;   // one float4 (524288 total)
    float4 v = ((const float4*)cb)[t];
    ushort4v h;
    h.x = f32_bf16_rn(v.x); h.y = f32_bf16_rn(v.y);
    h.z = f32_bf16_rn(v.z); h.w = f32_bf16_rn(v.w);
    *(ushort4v*)(Cbf + (size_t)t * 4) = h;
}

// ---------------- K3: np-exact sum of squares, wave-parallel.
// 16 lanes per row: lane (h,j) runs numpy's chain j of half h (16 serial
// adds, exact order), then shuffle tree ((r0+r1)+(r2+r3))+((r4+r5)+(r6+r7)),
// then blk0+blk1 -- bit-exact to np.add.reduce pairwise for n=256.
__global__ __launch_bounds__(256)
void sumsq_kernel(const float* __restrict__ rows, float* __restrict__ out, int nrows) {
    const int tid  = threadIdx.x;
    const int ln   = tid & 63;
    const int sub  = ln & 15;         // lane within row-group
    const int h    = sub >> 3;        // half: 0 or 1
    const int j    = sub & 7;         // chain id
    const int row  = blockIdx.x * 16 + (tid >> 4);
    if (row >= nrows) return;
    const float* p = rows + (size_t)row * 256 + h * 128 + j;
    float v = p[0];
    float r = mul_rn(v, v);
    #pragma unroll
    for (int i = 1; i < 16; ++i) {
        v = p[i * 8];
        r = add_rn(r, mul_rn(v, v));
    }
    float s = add_rn(r, __shfl_xor(r, 1, 64));
    s = add_rn(s, __shfl_xor(s, 2, 64));
    s = add_rn(s, __shfl_xor(s, 4, 64));   // lane j==0: blk[h]
    float o = __shfl_xor(s, 8, 64);
    if (sub == 0) out[row] = add_rn(s, o); // blk[0] + blk[1]
}

// ---------------- K5: bf16 MFMA screen, packed-key top-3 per (row, 128-block)
// key = mono(csq[k] - 2*dot_bf16) & ~127 | col(7b).  Outputs [block][n].
__global__ __launch_bounds__(256)
void screen_kernel(const unsigned short* __restrict__ Xbf,  // [16384][256]
                   const unsigned short* __restrict__ Cbf,  // [8192][256]
                   const float* __restrict__ csq,
                   unsigned* __restrict__ sv0, unsigned* __restrict__ sv1,
                   unsigned* __restrict__ sv2) {
    __shared__ unsigned lmk0[256], lmk1[256], lmk2[256];

    const int tid = threadIdx.x;
    const int w   = tid >> 6;
    const int ln  = tid & 63;
    const int bx = blockIdx.x, by = blockIdx.y;

    const int rh = (w & 1) * 64;    // wave's row half
    const int ch = (w >> 1) * 64;   // wave's col half

    const int row0 = bx * 128 + rh + (ln & 15);
    const int col0 = by * 128 + ch + (ln & 15);
    const int kq   = (ln >> 4) * 8;
    const unsigned short* pa = Xbf + (size_t)row0 * 256 + kq;
    const unsigned short* pb = Cbf + (size_t)col0 * 256 + kq;

    f32x4 acc[4][4] = {};
    bf16x8 aA[4], bA[4], aB[4], bB[4];

    // prologue: load ks=0
    #pragma unroll
    for (int t = 0; t < 4; ++t) {
        aA[t] = *(const bf16x8*)(pa + (size_t)(t * 16) * 256);
        bA[t] = *(const bf16x8*)(pb + (size_t)(t * 16) * 256);
    }
    // ping-pong software pipeline: load ks+1 while MFMA'ing ks
    #pragma unroll
    for (int ks = 0; ks < 8; ks += 2) {
        if (ks + 1 < 8) {
            const int kb = (ks + 1) * 32;
            #pragma unroll
            for (int t = 0; t < 4; ++t) {
                aB[t] = *(const bf16x8*)(pa + (size_t)(t * 16) * 256 + kb);
                bB[t] = *(const bf16x8*)(pb + (size_t)(t * 16) * 256 + kb);
            }
        }
        #pragma unroll
        for (int i = 0; i < 4; ++i)
            #pragma unroll
            for (int j = 0; j < 4; ++j)
                acc[i][j] = __builtin_amdgcn_mfma_f32_16x16x32_bf16(aA[i], bA[j], acc[i][j], 0, 0, 0);
        if (ks + 2 < 8) {
            const int kb = (ks + 2) * 32;
            #pragma unroll
            for (int t = 0; t < 4; ++t) {
                aA[t] = *(const bf16x8*)(pa + (size_t)(t * 16) * 256 + kb);
                bA[t] = *(const bf16x8*)(pb + (size_t)(t * 16) * 256 + kb);
            }
        }
        #pragma unroll
        for (int i = 0; i < 4; ++i)
            #pragma unroll
            for (int j = 0; j < 4; ++j)
                acc[i][j] = __builtin_amdgcn_mfma_f32_16x16x32_bf16(aB[i], bB[j], acc[i][j], 0, 0, 0);
    }

    float cq[4];
    #pragma unroll
    for (int j = 0; j < 4; ++j)
        cq[j] = csq[by * 128 + ch + j * 16 + (ln & 15)];

    #pragma unroll
    for (int i = 0; i < 4; ++i)
        #pragma unroll
        for (int r = 0; r < 4; ++r) {
            unsigned k[4];
            #pragma unroll
            for (int j = 0; j < 4; ++j) {
                float s = fmaf(-2.0f, acc[i][j][r], cq[j]);   // == rn(cq - 2*acc)
                k[j] = (mono_key(s) & 0xFFFFFF80u) | (unsigned)(ch + j * 16 + (ln & 15));
            }
            // sort4 -> smallest 3
            unsigned t0 = umin_(k[0], k[1]), t1 = umax_(k[0], k[1]);
            unsigned t2 = umin_(k[2], k[3]), t3 = umax_(k[2], k[3]);
            unsigned a0 = umin_(t0, t2);
            unsigned u  = umax_(t0, t2), v = umin_(t1, t3);
            unsigned a1 = umin_(u, v);
            unsigned a2 = umax_(u, v);
            // 16-lane butterfly merge of sorted triples
            #pragma unroll
            for (int m = 1; m < 16; m <<= 1) {
                unsigned b0 = __shfl_xor(a0, m, 64);
                unsigned b1 = __shfl_xor(a1, m, 64);
                unsigned b2 = __shfl_xor(a2, m, 64);
                unsigned uu = umax_(a0, b0), tt = umin_(a1, b1);
                unsigned n0 = umin_(a0, b0);
                unsigned n1 = umin_(uu, tt);
                unsigned n2 = umin_(umin_(a2, b2), umax_(uu, tt));
                a0 = n0; a1 = n1; a2 = n2;
            }
            if ((ln & 15) == 0) {
                int lrow = rh + i * 16 + (ln >> 4) * 4 + r;
                int half = w >> 1;
                lmk0[lrow * 2 + half] = a0;
                lmk1[lrow * 2 + half] = a1;
                lmk2[lrow * 2 + half] = a2;
            }
        }
    __syncthreads();
    if (tid < 128) {
        unsigned q0 = lmk0[tid * 2], q1 = lmk1[tid * 2], q2 = lmk2[tid * 2];
        unsigned p0 = lmk0[tid * 2 + 1], p1 = lmk1[tid * 2 + 1], p2 = lmk2[tid * 2 + 1];
        unsigned uu = umax_(q0, p0), tt = umin_(q1, p1);
        unsigned n0 = umin_(q0, p0);
        unsigned n1 = umin_(uu, tt);
        unsigned n2 = umin_(umin_(q2, p2), umax_(uu, tt));
        size_t o = (size_t)by * NROWS + bx * 128 + tid;
        sv0[o] = n0; sv1[o] = n1; sv2[o] = n2;
    }
}

// ---------------- K6: fused flag + exact rescore -> idx[n]  (1 wave / row)
__global__ __launch_bounds__(256)
void rescore_kernel(const float* __restrict__ xT, const float* __restrict__ cb,
                    const float* __restrict__ csq, const float* __restrict__ xsq,
                    const unsigned* __restrict__ sv0, const unsigned* __restrict__ sv1,
                    const unsigned* __restrict__ sv2,
                    int* __restrict__ idx) {
    const int tid = threadIdx.x;
    const int w = tid >> 6, ln = tid & 63;
    const int n = blockIdx.x * 4 + w;
    unsigned k0 = sv0[(size_t)ln * NROWS + n];
    unsigned k1 = sv1[(size_t)ln * NROWS + n];
    unsigned k2 = sv2[(size_t)ln * NROWS + n];
    // global min key over 64 blocks
    unsigned g = k0;
    #pragma unroll
    for (int m = 1; m < 64; m <<= 1) g = umin_(g, __shfl_xor(g, m, 64));
    float th = inv_mono(g & 0xFFFFFF80u) + MARGIN;
    unsigned th_key = mono_key(th) | 127u;
    unsigned long long m1 = __ballot(k0 <= th_key);   // block winner is candidate
    unsigned long long m2 = __ballot(k1 <= th_key);   // runner-up is candidate
    unsigned long long m3 = __ballot(k2 <= th_key);   // >=3 near-ties: full scan

    float4 xv = ((const float4*)xT)[(size_t)n * 64 + ln];
    const float xs = xsq[n];
    float bs = FLT_MAX;
    int   bk = 0x7fffffff;
    auto eval = [&](int k) {
        float4 cv = ((const float4*)cb)[(size_t)k * 64 + ln];
        double d = (double)cv.x * xv.x + (double)cv.y * xv.y
                 + (double)cv.z * xv.z + (double)cv.w * xv.w;
        #pragma unroll
        for (int m = 1; m < 64; m <<= 1) d += __shfl_xor(d, m, 64);
        float s = sub_rn(add_rn(xs, csq[k]), mul_rn(2.0f, (float)d));
        if (s < bs || (s == bs && k < bk)) { bs = s; bk = k; }
    };
    while (m1) {
        int b = (int)__builtin_ctzll(m1); m1 &= m1 - 1;
        unsigned kb = __shfl((int)k0, b, 64);
        eval(b * 128 + (int)(kb & 127u));
    }
    while (m2) {
        int b = (int)__builtin_ctzll(m2); m2 &= m2 - 1;
        unsigned kb = __shfl((int)k1, b, 64);
        eval(b * 128 + (int)(kb & 127u));
    }
    while (m3) {   // rare rigorous fallback
        int b = (int)__builtin_ctzll(m3); m3 &= m3 - 1;
        for (int kk = 0; kk < 128; ++kk) eval(b * 128 + kk);
    }
    if (ln == 0) idx[n] = bk;
}

// ---------------- K7: quantized gather back to (B,C,H,W)
__global__ __launch_bounds__(256)
void gather_quant_kernel(const float* __restrict__ cb, const int* __restrict__ idx,
                         float* __restrict__ out0) {
    int t = blockIdx.x * 256 + threadIdx.x;
    int hw4 = t & 255;
    int d   = (t >> 8) & 255;
    int b   = t >> 16;
    int n0  = b * BHW + hw4 * 4;
    float4 o;
    o.x = cb[(size_t)idx[n0 + 0] * D + d];
    o.y = cb[(size_t)idx[n0 + 1] * D + d];
    o.z = cb[(size_t)idx[n0 + 2] * D + d];
    o.w = cb[(size_t)idx[n0 + 3] * D + d];
    ((float4*)out0)[t] = o;
}

// ---------------- K8: one-hot fill
__global__ __launch_bounds__(256)
void onehot_kernel(const int* __restrict__ idx, float* __restrict__ out1) {
    int t = blockIdx.x * 256 + threadIdx.x;
    int n  = t >> 11;
    int k0 = (t & 2047) * 4;
    int target = idx[n];
    float4 v = {0.f, 0.f, 0.f, 0.f};
    int r = target - k0;
    if (r >= 0 && r < 4) ((float*)&v)[r] = 1.0f;
    ((float4*)out1)[t] = v;
}

// ------------------------------------------------------------------ launch
extern "C" void kernel_launch(void* const* d_in, const int* in_sizes, int n_in,
                              void* d_out, int out_size, void* d_ws, size_t ws_size,
                              hipStream_t stream) {
    const float* x  = (const float*)d_in[0];   // [16][256][32][32]
    const float* cb = (const float*)d_in[1];   // [8192][256]
    float* out0 = (float*)d_out;                       // quantized
    float* out1 = (float*)d_out + 4194304;             // one_hot (537 MB)

    // small scratch in ws
    char* ws = (char*)d_ws;
    float* csq  = (float*)(ws + 0);            //  32 KB
    float* xsq  = (float*)(ws + 32768);        //  64 KB
    int*   idx  = (int*)  (ws + 98304);        //  64 KB

    // big scratch in the one_hot region (fully overwritten last by onehot)
    char* sc = (char*)out1;
    unsigned short* Xbf = (unsigned short*)sc;                   //  8 MB
    unsigned short* Cbf = (unsigned short*)(sc + 8388608);       //  4 MB
    float* xT  = (float*)(sc + 12582912);                        // 16 MB
    unsigned* sv0 = (unsigned*)(sc + 29360128);                  //  4 MB
    unsigned* sv1 = (unsigned*)(sc + 33554432);                  //  4 MB
    unsigned* sv2 = (unsigned*)(sc + 37748736);                  //  4 MB

    prep_x_kernel<<<4096, 256, 0, stream>>>(x, xT, Xbf);
    prep_c_kernel<<<2048, 256, 0, stream>>>(cb, Cbf);
    sumsq_kernel<<<K / 16, 256, 0, stream>>>(cb, csq, K);
    sumsq_kernel<<<NROWS / 16, 256, 0, stream>>>(xT, xsq, NROWS);

    dim3 sgrid(NROWS / 128, K / 128);   // 128 x 64
    screen_kernel<<<sgrid, 256, 0, stream>>>(Xbf, Cbf, csq, sv0, sv1, sv2);

    rescore_kernel<<<NROWS / 4, 256, 0, stream>>>(xT, cb, csq, xsq, sv0, sv1, sv2, idx);

    gather_quant_kernel<<<(4194304 / 4) / 256, 256, 0, stream>>>(cb, idx, out0);
    onehot_kernel<<<(134217728 / 4) / 256, 256, 0, stream>>>(idx, out1);
}